// Round 6
// baseline (61.507 us; speedup 1.0000x reference)
//
#include <hip/hip_runtime.h>

#define GG 1000
#define NPG 500
#define KK 8
#define N1 128
#define N2 128
#define NEG_SLOPE 0.45f
#define NTHREADS 512
#define NWAVES 8

__global__ __launch_bounds__(NTHREADS) void cluster_attn_kernel(
    const float* __restrict__ x,
    const float* __restrict__ W1,
    const float* __restrict__ b1,
    const float* __restrict__ Wa,
    const float* __restrict__ ba,
    const int*   __restrict__ cls,
    float*       __restrict__ out)
{
    __shared__ float s_acc[KK + 1][N1];    // 4.5 KB; [8] is the dummy bucket
    __shared__ float s_hw[KK * N2];        // 4 KB
    __shared__ int   s_cls[NPG];           // 2 KB
    __shared__ int   s_order[NTHREADS];    // 2 KB: node | (cluster<<12), sorted, padded
    __shared__ int   s_wcnt[NWAVES][KK];
    __shared__ int   s_start[KK];
    __shared__ float s_fcnt[KK];
    __shared__ float s_ratio[KK];
    __shared__ float s_L[KK];
    __shared__ float s_e[KK];

    const int g   = blockIdx.x;
    const int tid = threadIdx.x;
    const int w   = tid >> 6;     // wave 0..7
    const int l   = tid & 63;     // lane
    const bool hi = l >= 32;      // upper half-wave
    const int qb  = (l & 31) * 16;// byte offset within a 512B node row

    const int* clsg = cls + (size_t)g * NPG;
    float* accf = &s_acc[0][0];
    for (int i = tid; i < (KK + 1) * N1; i += NTHREADS) accf[i] = 0.f;

    int myc = -1;
    if (tid < NPG) { myc = clsg[tid]; s_cls[tid] = myc; }

    // ---- deterministic bucket ranks via wave ballots (no atomics) ----
    unsigned long long mymask = 0;
    #pragma unroll
    for (int k = 0; k < KK; ++k) {
        unsigned long long m = __ballot(myc == k);
        if (l == 0) s_wcnt[w][k] = (int)__popcll(m);
        if (myc == k) mymask = m;
    }
    __syncthreads();

    if (tid == 0) {                         // totals, bucket starts, ratios
        int run = 0; float d = 0.f;
        #pragma unroll
        for (int k = 0; k < KK; ++k) {
            int t = 0;
            #pragma unroll
            for (int ww = 0; ww < NWAVES; ++ww) t += s_wcnt[ww][k];
            s_start[k] = run; run += t;
            float c = (float)t; s_fcnt[k] = c; d += c * c;
        }
        #pragma unroll
        for (int k = 0; k < KK; ++k) s_ratio[k] = s_fcnt[k] / d;
    }
    __syncthreads();

    if (tid < NPG) {                        // deterministic scatter into sorted order
        int before = 0;
        for (int ww = 0; ww < w; ++ww) before += s_wcnt[ww][myc];
        before += (int)__popcll(mymask & ((1ULL << l) - 1ULL));
        s_order[s_start[myc] + before] = tid | (myc << 12);
    } else {
        s_order[tid] = 0 | (8 << 12);       // dummy: node 0, bucket 8 (discarded)
    }
    __syncthreads();

    // ---- phase 1: dwordx4 loads, 2 node rows per wave-instr, register runs ----
    const int ordreg = s_order[(w << 6) | l];   // lane i: entry i of wave's chunk
    const char* xrow = (const char*)(x + (size_t)g * NPG * N1);

    float a0 = 0.f, a1 = 0.f, a2 = 0.f, a3 = 0.f;
    int cur0 = __builtin_amdgcn_readlane(ordreg, 0)  >> 12;
    int cur1 = __builtin_amdgcn_readlane(ordreg, 32) >> 12;

#define FLUSH(C)                                                         \
    {                                                                    \
        atomicAdd(&s_acc[C][(l & 31) * 4 + 0], a0);                      \
        atomicAdd(&s_acc[C][(l & 31) * 4 + 1], a1);                      \
        atomicAdd(&s_acc[C][(l & 31) * 4 + 2], a2);                      \
        atomicAdd(&s_acc[C][(l & 31) * 4 + 3], a3);                      \
        a0 = 0.f; a1 = 0.f; a2 = 0.f; a3 = 0.f;                          \
    }
#define LOADP(P, E)                                                      \
    const int olo##P = __builtin_amdgcn_readlane(ordreg, (E));           \
    const int ohi##P = __builtin_amdgcn_readlane(ordreg, 32 + (E));      \
    const int nd##P  = hi ? (ohi##P & 0xFFF) : (olo##P & 0xFFF);         \
    const float4 v##P = *(const float4*)(xrow + ((size_t)nd##P << 9) + qb);
#define PROC(P)                                                          \
    {                                                                    \
        const int clo = olo##P >> 12, chi = ohi##P >> 12;                \
        if (clo != cur0) { if (!hi) FLUSH(cur0); cur0 = clo; }           \
        if (chi != cur1) { if (hi)  FLUSH(cur1); cur1 = chi; }           \
        a0 += v##P.x; a1 += v##P.y; a2 += v##P.z; a3 += v##P.w;          \
    }

    #pragma unroll 2
    for (int it = 0; it < 8; ++it) {
        const int e = it * 4;
        LOADP(0, e) LOADP(1, e + 1) LOADP(2, e + 2) LOADP(3, e + 3)
        PROC(0) PROC(1) PROC(2) PROC(3)
    }
    if (!hi) FLUSH(cur0);
    if (hi)  FLUSH(cur1);
#undef PROC
#undef LOADP
#undef FLUSH
    __syncthreads();

    // ---- phase 2: h[k][j] = leaky(ratio_k*(csum_k . W1[:,j]) + b1[j]);
    //      hw[k][j] = h[k][j]*Wa[j]  (1024 dots over 512 threads) ----
    #pragma unroll
    for (int r = 0; r < 2; ++r) {
        int idx = tid + r * NTHREADS;        // 0..1023
        int k = idx >> 7;
        int j = idx & 127;
        float s = 0.f;
        #pragma unroll 4
        for (int f = 0; f < N1; ++f)
            s = fmaf(accf[k * N1 + f], W1[f * N2 + j], s);
        float val = fmaf(s, s_ratio[k], b1[j]);
        float h = val > 0.f ? val : NEG_SLOPE * val;
        s_hw[idx] = h * Wa[j];
    }
    __syncthreads();

    // ---- per-k reduce: wave w owns cluster k=w ----
    {
        float v = s_hw[w * 128 + l] + s_hw[w * 128 + 64 + l];
        #pragma unroll
        for (int off = 32; off > 0; off >>= 1) v += __shfl_down(v, off);
        if (l == 0) s_L[w] = v + ba[0];
    }
    __syncthreads();

    // ---- phase 3: count-weighted softmax over 8 clusters (skip empty) ----
    if (tid == 0) {
        float m = -1e30f;
        #pragma unroll
        for (int k = 0; k < KK; ++k)
            if (s_fcnt[k] > 0.f) m = fmaxf(m, s_L[k]);
        float ssum = 0.f;
        float ek[KK];
        #pragma unroll
        for (int k = 0; k < KK; ++k) {
            ek[k] = (s_fcnt[k] > 0.f) ? expf(s_L[k] - m) : 0.f;
            ssum += s_fcnt[k] * ek[k];
        }
        #pragma unroll
        for (int k = 0; k < KK; ++k) s_e[k] = ek[k] / ssum;
    }
    __syncthreads();

    // ---- phase 4: per-node output = table lookup from staged cls ----
    float* outg = out + (size_t)g * NPG;
    for (int n = tid; n < NPG; n += NTHREADS) outg[n] = s_e[s_cls[n]];
}

extern "C" void kernel_launch(void* const* d_in, const int* in_sizes, int n_in,
                              void* d_out, int out_size, void* d_ws, size_t ws_size,
                              hipStream_t stream) {
    const float* x   = (const float*)d_in[0];
    const float* W1  = (const float*)d_in[1];
    const float* b1  = (const float*)d_in[2];
    const float* Wa  = (const float*)d_in[3];
    const float* ba  = (const float*)d_in[4];
    const int*   cls = (const int*)d_in[5];
    // d_in[6] = batch: sorted repeat(arange(G), NPG) by construction -> implicit

    float* out = (float*)d_out;
    cluster_attn_kernel<<<GG, NTHREADS, 0, stream>>>(x, W1, b1, Wa, ba, cls, out);
}

// Round 7
// 55.323 us; speedup vs baseline: 1.1118x; 1.1118x over previous
//
#include <hip/hip_runtime.h>

#define GG 1000
#define NPG 500
#define KK 8
#define N1 128
#define N2 128
#define NEG_SLOPE 0.45f
#define NTHREADS 512
#define NWAVES 8
#define CHUNK ((NPG + NWAVES - 1) / NWAVES)   // 63

__global__ __launch_bounds__(NTHREADS) void cluster_attn_kernel(
    const float* __restrict__ x,
    const float* __restrict__ W1,
    const float* __restrict__ b1,
    const float* __restrict__ Wa,
    const float* __restrict__ ba,
    const int*   __restrict__ cls,
    float*       __restrict__ out)
{
    __shared__ float s_acc[KK][N1];        // 4 KB shared csum (rare atomic flushes)
    __shared__ int   s_cls[NPG];           // 2 KB
    __shared__ int   s_order[NPG];         // 2 KB: node | (cluster<<12), cluster-sorted
    __shared__ int   s_wcnt[NWAVES][KK];   // per-wave cluster histograms
    __shared__ int   s_start[KK];
    __shared__ float s_Lp[NWAVES][KK];     // per-wave partial logits
    __shared__ float s_fcnt[KK];
    __shared__ float s_ratio[KK];
    __shared__ float s_e[KK];

    const int g   = blockIdx.x;
    const int tid = threadIdx.x;
    const int w   = tid >> 6;     // wave 0..7
    const int l   = tid & 63;     // lane

    const int* clsg = cls + (size_t)g * NPG;
    float* accf = &s_acc[0][0];
    for (int i = tid; i < KK * N1; i += NTHREADS) accf[i] = 0.f;

    int myc = -1;
    if (tid < NPG) { myc = clsg[tid]; s_cls[tid] = myc; }

    // ---- deterministic bucket ranks via wave ballots (no atomics) ----
    unsigned long long mymask = 0;
    #pragma unroll
    for (int k = 0; k < KK; ++k) {
        unsigned long long m = __ballot(myc == k);
        if (l == 0) s_wcnt[w][k] = (int)__popcll(m);
        if (myc == k) mymask = m;
    }
    __syncthreads();

    if (tid == 0) {                         // totals, bucket starts, ratios
        int run = 0; float d = 0.f;
        #pragma unroll
        for (int k = 0; k < KK; ++k) {
            int t = 0;
            #pragma unroll
            for (int ww = 0; ww < NWAVES; ++ww) t += s_wcnt[ww][k];
            s_start[k] = run; run += t;
            float c = (float)t; s_fcnt[k] = c; d += c * c;
        }
        #pragma unroll
        for (int k = 0; k < KK; ++k) s_ratio[k] = s_fcnt[k] / d;
    }
    __syncthreads();

    if (tid < NPG) {                        // deterministic scatter into sorted order
        int before = 0;
        for (int ww = 0; ww < w; ++ww) before += s_wcnt[ww][myc];
        before += (int)__popcll(mymask & ((1ULL << l) - 1ULL));
        s_order[s_start[myc] + before] = tid | (myc << 12);
    }
    __syncthreads();

    // ---- phase 1: wave walks a contiguous cluster-sorted chunk.
    //      Inner loop = load + 2 v_add. Flush only on (rare) run boundary. ----
    const float2* x2 = (const float2*)(x + (size_t)g * NPG * N1);
    {
        int begin = w * CHUNK;
        int end   = begin + CHUNK; if (end > NPG) end = NPG;
        if (begin < end) {
            int cur = __builtin_amdgcn_readfirstlane(s_order[begin]) >> 12;
            float a0 = 0.f, a1 = 0.f;
            int e = begin;

#define STEP(P, V)                                                      \
            {                                                           \
                int c_ = (P) >> 12;                                     \
                if (c_ != cur) {            /* wave-uniform, rare */    \
                    atomicAdd(&s_acc[cur][2 * l],     a0);              \
                    atomicAdd(&s_acc[cur][2 * l + 1], a1);              \
                    a0 = 0.f; a1 = 0.f; cur = c_;                       \
                }                                                       \
                a0 += (V).x; a1 += (V).y;                               \
            }

            for (; e + 4 <= end; e += 4) {
                int p0 = __builtin_amdgcn_readfirstlane(s_order[e]);
                int p1 = __builtin_amdgcn_readfirstlane(s_order[e + 1]);
                int p2 = __builtin_amdgcn_readfirstlane(s_order[e + 2]);
                int p3 = __builtin_amdgcn_readfirstlane(s_order[e + 3]);
                float2 v0 = x2[(size_t)(p0 & 0xFFF) * 64 + l];   // 4x512B in flight
                float2 v1 = x2[(size_t)(p1 & 0xFFF) * 64 + l];
                float2 v2 = x2[(size_t)(p2 & 0xFFF) * 64 + l];
                float2 v3 = x2[(size_t)(p3 & 0xFFF) * 64 + l];
                STEP(p0, v0) STEP(p1, v1) STEP(p2, v2) STEP(p3, v3)
            }
            for (; e < end; ++e) {
                int p = __builtin_amdgcn_readfirstlane(s_order[e]);
                float2 v = x2[(size_t)(p & 0xFFF) * 64 + l];
                STEP(p, v)
            }
#undef STEP
            atomicAdd(&s_acc[cur][2 * l],     a0);   // final run flush
            atomicAdd(&s_acc[cur][2 * l + 1], a1);
        }
    }
    __syncthreads();

    // ---- phase 2 (W1 read ONCE per block): wave w owns j-tile [16w,16w+16).
    //      lane = (j = 16w+(l&15), f-group = l>>4); each W1 value reused 8x ----
    {
        const int   jt  = (w << 4) + (l & 15);
        const int   fg  = l >> 4;               // 0..3, covers f in [32fg, 32fg+32)
        const float b1j = b1[jt];
        const float Waj = Wa[jt];
        float p[KK];
        #pragma unroll
        for (int k = 0; k < KK; ++k) p[k] = 0.f;

        const float* w1p = W1 + (size_t)(fg * 32) * N2 + jt;
        #pragma unroll 4
        for (int i = 0; i < 32; ++i) {
            const float wv = w1p[(size_t)i * N2];   // 4x64B segments / wave-instr
            const int   f  = fg * 32 + i;
            #pragma unroll
            for (int k = 0; k < KK; ++k)
                p[k] = fmaf(accf[k * N1 + f], wv, p[k]);  // LDS broadcast x4 groups
        }
        #pragma unroll
        for (int k = 0; k < KK; ++k) {
            float v = p[k];
            v += __shfl_xor(v, 16);
            v += __shfl_xor(v, 32);              // full dot[k][jt], replicated x4
            float val = fmaf(v, s_ratio[k], b1j);
            float h = val > 0.f ? val : NEG_SLOPE * val;
            float c = h * Waj;
            c += __shfl_xor(c, 1);
            c += __shfl_xor(c, 2);
            c += __shfl_xor(c, 4);
            c += __shfl_xor(c, 8);               // sum over the tile's 16 j's
            if (l == 0) s_Lp[w][k] = c;
        }
    }
    __syncthreads();

    // ---- phase 3: logits = sum of per-wave partials; count-weighted softmax ----
    if (tid == 0) {
        float Lk[KK];
        #pragma unroll
        for (int k = 0; k < KK; ++k) {
            float s = ba[0];
            #pragma unroll
            for (int ww = 0; ww < NWAVES; ++ww) s += s_Lp[ww][k];
            Lk[k] = s;
        }
        float m = -1e30f;
        #pragma unroll
        for (int k = 0; k < KK; ++k)
            if (s_fcnt[k] > 0.f) m = fmaxf(m, Lk[k]);
        float ssum = 0.f;
        float ek[KK];
        #pragma unroll
        for (int k = 0; k < KK; ++k) {
            ek[k] = (s_fcnt[k] > 0.f) ? expf(Lk[k] - m) : 0.f;
            ssum += s_fcnt[k] * ek[k];
        }
        #pragma unroll
        for (int k = 0; k < KK; ++k) s_e[k] = ek[k] / ssum;
    }
    __syncthreads();

    // ---- phase 4: per-node output = table lookup from staged cls ----
    float* outg = out + (size_t)g * NPG;
    for (int n = tid; n < NPG; n += NTHREADS) outg[n] = s_e[s_cls[n]];
}

extern "C" void kernel_launch(void* const* d_in, const int* in_sizes, int n_in,
                              void* d_out, int out_size, void* d_ws, size_t ws_size,
                              hipStream_t stream) {
    const float* x   = (const float*)d_in[0];
    const float* W1  = (const float*)d_in[1];
    const float* b1  = (const float*)d_in[2];
    const float* Wa  = (const float*)d_in[3];
    const float* ba  = (const float*)d_in[4];
    const int*   cls = (const int*)d_in[5];
    // d_in[6] = batch: sorted repeat(arange(G), NPG) by construction -> implicit

    float* out = (float*)d_out;
    cluster_attn_kernel<<<GG, NTHREADS, 0, stream>>>(x, W1, b1, Wa, ba, cls, out);
}